// Round 3
// baseline (87.422 us; speedup 1.0000x reference)
//
#include <hip/hip_runtime.h>
#include <math.h>

// Problem constants (fixed by reference)
constexpr int N_ = 4, P_ = 64, Z_ = 32, Y_ = 128, X_ = 128;
constexpr float EPSF = 1e-8f;
constexpr float INV2S2 = 0.125f;   // 1/(2*sigma^2), sigma = 2

// Workspace layout (floats). kz/ky are stored TRANSPOSED (coord-major,
// p-minor) so k_main's kzy-tile fill reads coalesced 256B segments.
constexpr int KZ_OFF = 0;                          // [N][Z][P]   8192
constexpr int KY_OFF = KZ_OFF + N_ * Z_ * P_;      // [N][Y][P]  32768
constexpr int KX_OFF = KY_OFF + N_ * Y_ * P_;      // [N][P][X]  32768
constexpr int M_OFF  = KX_OFF + N_ * P_ * X_;      // [N][P]       256
constexpr int TBL_ELEMS = N_ * P_ * (Z_ + Y_ + X_); // 73728

// ---------------------------------------------------------------------------
// Kernel 1: separable Gaussian tables + zero the m accumulator.
// K = exp(-dz^2/8)*exp(-dy^2/8)*exp(-dx^2/8); EPS=1e-8 denominator floor means
// only K >= ~1e-10 matters, where every factor is normal fp32 -> product
// matches the reference's single exp to ~ulp.
// ---------------------------------------------------------------------------
__global__ __launch_bounds__(256) void k_tables(const float* __restrict__ pts,
                                                float* __restrict__ ws) {
    int idx = blockIdx.x * 256 + threadIdx.x;
    if (idx < N_ * P_) ws[M_OFF + idx] = 0.0f;   // ws is poisoned each call
    if (idx < N_ * Z_ * P_) {                    // (n, z, p) order
        int n = idx / (Z_ * P_); int r = idx % (Z_ * P_);
        int c = r / P_; int p = r % P_;
        float d = (float)c - pts[(n * P_ + p) * 3 + 0];
        ws[KZ_OFF + idx] = expf(-d * d * INV2S2);
    } else if (idx < N_ * Z_ * P_ + N_ * Y_ * P_) {  // (n, y, p) order
        int j = idx - N_ * Z_ * P_;
        int n = j / (Y_ * P_); int r = j % (Y_ * P_);
        int c = r / P_; int p = r % P_;
        float d = (float)c - pts[(n * P_ + p) * 3 + 1];
        ws[KY_OFF + j] = expf(-d * d * INV2S2);
    } else if (idx < TBL_ELEMS) {                    // (n, p, x) order
        int j = idx - (N_ * Z_ * P_ + N_ * Y_ * P_);
        int n = j / (P_ * X_); int r = j % (P_ * X_);
        int p = r / X_; int c = r % X_;
        float d = (float)c - pts[(n * P_ + p) * 3 + 2];
        ws[KX_OFF + j] = expf(-d * d * INV2S2);
    }
}

// ---------------------------------------------------------------------------
// Kernel 2: per-voxel denom + m accumulation.
// Grid: 512 blocks = (n, z, y-half, x-half) -> 2 blocks/CU, 8 waves/CU
// (R2 ran 1 block/CU = 4 waves/CU; latency-bound). Block: 256 threads,
// each wave owns one y-row per pass (16 passes), each thread one x-column.
// kkx[p] = kzy[row][p]*kx[p][x] is computed ONCE per pass: denom is its
// 4-way-partial sum (breaks the 64-deep FMA chain), macc += kkx*w reuses it
// (halves LDS reads vs R2). Next row's logit is prefetched one pass ahead.
// VGPR state: kxr[64]+macc[64]+kkx[64] ~= 210 -> fits 2 waves/EU (256 cap).
// ---------------------------------------------------------------------------
__global__ __launch_bounds__(256, 2) void k_main(const float* __restrict__ logits,
                                                 float* __restrict__ ws) {
    const float* kzT = ws + KZ_OFF;
    const float* kyT = ws + KY_OFF;
    const float* kx  = ws + KX_OFF;
    float* m = ws + M_OFF;

    const int b = blockIdx.x;          // 512 blocks: [n:2][z:5][yh:1][xh:1]
    const int n  = b >> 7;
    const int z  = (b >> 2) & 31;
    const int y0 = ((b >> 1) & 1) * 64;
    const int x0 = (b & 1) * 64;

    const int tid = threadIdx.x;
    const int lane = tid & 63;
    const int wid = tid >> 6;

    __shared__ float kzy[64 * 64];     // [row][p], 16 KB
    __shared__ float wsum[4][64];

    for (int i = tid; i < 64 * 64; i += 256) {
        int row = i >> 6, p = i & 63;  // both reads coalesced (p-minor tables)
        kzy[i] = kzT[(n * Z_ + z) * P_ + p] * kyT[(n * Y_ + (y0 + row)) * P_ + p];
    }

    const int x = x0 + lane;
    float kxr[64], macc[64];
    #pragma unroll
    for (int p = 0; p < 64; ++p) {
        kxr[p] = kx[(n * P_ + p) * X_ + x];   // coalesced 256B per p
        macc[p] = 0.0f;
    }
    __syncthreads();

    const float* lbase = logits + (size_t)((n * Z_ + z) * Y_ + y0) * X_ + x;

    float lg = lbase[wid * X_];        // prefetch pass-0 logit
    #pragma unroll 1
    for (int pass = 0; pass < 16; ++pass) {
        const int row = pass * 4 + wid;           // wave-uniform row
        float lg_next = 0.0f;
        if (pass < 15) lg_next = lbase[(row + 4) * X_];   // prefetch next pass

        const float4* kr = (const float4*)(&kzy[row * 64]);
        float kkx[64];
        float d0 = 0.f, d1 = 0.f, d2 = 0.f, d3 = 0.f;
        #pragma unroll
        for (int q = 0; q < 16; ++q) {
            const float4 k4 = kr[q];              // broadcast b128 read
            kkx[4*q+0] = k4.x * kxr[4*q+0]; d0 += kkx[4*q+0];
            kkx[4*q+1] = k4.y * kxr[4*q+1]; d1 += kkx[4*q+1];
            kkx[4*q+2] = k4.z * kxr[4*q+2]; d2 += kkx[4*q+2];
            kkx[4*q+3] = k4.w * kxr[4*q+3]; d3 += kkx[4*q+3];
        }
        const float denom = (d0 + d1) + (d2 + d3);
        // w = sigmoid(lg) / max(denom, EPS): one fp32 divide
        const float w = 1.0f / ((1.0f + __expf(-lg)) * fmaxf(denom, EPSF));

        #pragma unroll
        for (int p = 0; p < 64; ++p) macc[p] = fmaf(kkx[p], w, macc[p]);
        lg = lg_next;
    }

    // Reduce macc[p] across the 64 lanes of each wave, then across waves.
    #pragma unroll
    for (int p = 0; p < 64; ++p) {
        float v = macc[p];
        #pragma unroll
        for (int off = 32; off > 0; off >>= 1) v += __shfl_xor(v, off, 64);
        macc[p] = v;
    }
    if (lane == 0) {
        #pragma unroll
        for (int p = 0; p < 64; ++p) wsum[wid][p] = macc[p];
    }
    __syncthreads();
    if (tid < 64) {
        float s = wsum[0][tid] + wsum[1][tid] + wsum[2][tid] + wsum[3][tid];
        atomicAdd(&m[n * P_ + tid], s);   // 64 atomics/block, 512 blocks
    }
}

// ---------------------------------------------------------------------------
// Kernel 3: loss = mean_{n,p} -log(max(m, EPS))   (N*P = 256 == block size)
// ---------------------------------------------------------------------------
__global__ __launch_bounds__(256) void k_loss(const float* __restrict__ m,
                                              float* __restrict__ out) {
    int t = threadIdx.x;
    float l = -logf(fmaxf(m[t], EPSF));
    #pragma unroll
    for (int off = 32; off > 0; off >>= 1) l += __shfl_xor(l, off, 64);
    __shared__ float red[4];
    if ((t & 63) == 0) red[t >> 6] = l;
    __syncthreads();
    if (t == 0) out[0] = (red[0] + red[1] + red[2] + red[3]) * (1.0f / 256.0f);
}

extern "C" void kernel_launch(void* const* d_in, const int* in_sizes, int n_in,
                              void* d_out, int out_size, void* d_ws, size_t ws_size,
                              hipStream_t stream) {
    const float* logits = (const float*)d_in[0];  // [4,1,32,128,128] fp32
    const float* pts    = (const float*)d_in[1];  // [4,64,3] fp32
    float* ws  = (float*)d_ws;                    // needs 73984 floats (~289 KB)
    float* out = (float*)d_out;                   // scalar fp32

    k_tables<<<dim3((TBL_ELEMS + 255) / 256), dim3(256), 0, stream>>>(pts, ws);
    k_main<<<dim3(512), dim3(256), 0, stream>>>(logits, ws);
    k_loss<<<dim3(1), dim3(256), 0, stream>>>(ws + M_OFF, out);
}

// Round 4
// 85.355 us; speedup vs baseline: 1.0242x; 1.0242x over previous
//
#include <hip/hip_runtime.h>
#include <math.h>

// Problem constants (fixed by reference)
constexpr int N_ = 4, P_ = 64, Z_ = 32, Y_ = 128, X_ = 128;
constexpr float EPSF = 1e-8f;
constexpr float INV2S2 = 0.125f;   // 1/(2*sigma^2), sigma = 2

// ---------------------------------------------------------------------------
// Fused kernel: Gaussian tables (computed in-register/LDS via separability),
// per-voxel denom + m accumulation, per-block partial written to a PRIVATE
// workspace slot (full overwrite -> no pre-zero needed despite 0xAA poison,
// and no atomics).
//
// Grid: 512 blocks = (n, z, y-half, x-half); 256 threads = 4 waves.
// Each wave owns one y-row per pass (16 passes), each thread one x-column.
// K factors: kzy[row][p] = exp(-((z-pz)^2+(y-py)^2)/8) in LDS (4096 exps per
// block, 16/thread); kxr[p] = exp(-(x-px)^2/8) in VGPRs (64/thread). Product
// of 2 exps == reference's single exp to ~ulp wherever K exceeds the 1e-8
// denominator floor (both factors >= e^-25, fully normal fp32).
// kkx[p] = kzy*kxr computed once/pass: denom = 4-way partial sum of it,
// macc += kkx*w reuses it (one LDS read pass, one fp32 divide per voxel).
// VGPR state kxr[64]+macc[64]+kkx[64] ~= 210 -> __launch_bounds__(256,2)
// (cap 256), 2 blocks/CU.
// ---------------------------------------------------------------------------
__global__ __launch_bounds__(256, 2) void k_fused(const float* __restrict__ logits,
                                                  const float* __restrict__ pts,
                                                  float* __restrict__ part) {
    const int b = blockIdx.x;          // 512 blocks: [n:2][z:5][yh:1][xh:1]
    const int n  = b >> 7;
    const int z  = (b >> 2) & 31;
    const int y0 = ((b >> 1) & 1) * 64;
    const int x0 = (b & 1) * 64;

    const int tid = threadIdx.x;
    const int lane = tid & 63;
    const int wid = tid >> 6;

    __shared__ float ptsn[192];        // pts[n] = [64][3]
    __shared__ float kzy[64 * 64];     // [row][p], 16 KB
    __shared__ float wsum[4][64];

    if (tid < 192) ptsn[tid] = pts[n * 192 + tid];
    __syncthreads();

    // kzy tile: 4096 exps / 256 threads = 16 per thread.
    for (int i = tid; i < 64 * 64; i += 256) {
        int row = i >> 6, p = i & 63;  // ptsn stride-3 reads: 2-way LDS alias = free
        float dz = (float)z - ptsn[p * 3 + 0];
        float dy = (float)(y0 + row) - ptsn[p * 3 + 1];
        kzy[i] = expf(-(dz * dz + dy * dy) * INV2S2);
    }

    const int x = x0 + lane;
    float kxr[64], macc[64];
    #pragma unroll
    for (int p = 0; p < 64; ++p) {
        float dx = (float)x - ptsn[p * 3 + 2];
        kxr[p] = expf(-dx * dx * INV2S2);
        macc[p] = 0.0f;
    }
    __syncthreads();

    const float* lbase = logits + (size_t)((n * Z_ + z) * Y_ + y0) * X_ + x;

    float lg = lbase[wid * X_];        // prefetch pass-0 logit
    #pragma unroll 1
    for (int pass = 0; pass < 16; ++pass) {
        const int row = pass * 4 + wid;           // wave-uniform row
        float lg_next = 0.0f;
        if (pass < 15) lg_next = lbase[(row + 4) * X_];   // prefetch next pass

        const float4* kr = (const float4*)(&kzy[row * 64]);
        float kkx[64];
        float d0 = 0.f, d1 = 0.f, d2 = 0.f, d3 = 0.f;
        #pragma unroll
        for (int q = 0; q < 16; ++q) {
            const float4 k4 = kr[q];              // broadcast b128 read
            kkx[4*q+0] = k4.x * kxr[4*q+0]; d0 += kkx[4*q+0];
            kkx[4*q+1] = k4.y * kxr[4*q+1]; d1 += kkx[4*q+1];
            kkx[4*q+2] = k4.z * kxr[4*q+2]; d2 += kkx[4*q+2];
            kkx[4*q+3] = k4.w * kxr[4*q+3]; d3 += kkx[4*q+3];
        }
        const float denom = (d0 + d1) + (d2 + d3);
        // w = sigmoid(lg) / max(denom, EPS): one fp32 divide
        const float w = 1.0f / ((1.0f + __expf(-lg)) * fmaxf(denom, EPSF));

        #pragma unroll
        for (int p = 0; p < 64; ++p) macc[p] = fmaf(kkx[p], w, macc[p]);
        lg = lg_next;
    }

    // Reduce macc[p] across the 64 lanes of each wave, then across waves.
    #pragma unroll
    for (int p = 0; p < 64; ++p) {
        float v = macc[p];
        #pragma unroll
        for (int off = 32; off > 0; off >>= 1) v += __shfl_xor(v, off, 64);
        macc[p] = v;
    }
    if (lane == 0) {
        #pragma unroll
        for (int p = 0; p < 64; ++p) wsum[wid][p] = macc[p];
    }
    __syncthreads();
    if (tid < 64) {
        float s = wsum[0][tid] + wsum[1][tid] + wsum[2][tid] + wsum[3][tid];
        part[b * 64 + tid] = s;        // private slot: plain store, no atomic
    }
}

// ---------------------------------------------------------------------------
// Finish kernel: m[n][p] = sum over that n's 128 blocks of partials, then
// loss = mean_{n,p} -log(max(m, EPS)). 1 block, 256 threads (t = n*64+p).
// Reads 128 KB of just-written partials (L2-hot), coalesced 256B rows.
// ---------------------------------------------------------------------------
__global__ __launch_bounds__(256) void k_finish(const float* __restrict__ part,
                                                float* __restrict__ out) {
    const int t = threadIdx.x;
    const int n = t >> 6, p = t & 63;
    const float* base = part + (size_t)(n * 128) * 64 + p;
    float s0 = 0.f, s1 = 0.f, s2 = 0.f, s3 = 0.f;
    #pragma unroll 4
    for (int j = 0; j < 128; j += 4) {     // independent accumulators
        s0 += base[(j + 0) * 64];
        s1 += base[(j + 1) * 64];
        s2 += base[(j + 2) * 64];
        s3 += base[(j + 3) * 64];
    }
    const float m = (s0 + s1) + (s2 + s3);
    float l = -logf(fmaxf(m, EPSF));
    #pragma unroll
    for (int off = 32; off > 0; off >>= 1) l += __shfl_xor(l, off, 64);
    __shared__ float red[4];
    if ((t & 63) == 0) red[t >> 6] = l;
    __syncthreads();
    if (t == 0) out[0] = (red[0] + red[1] + red[2] + red[3]) * (1.0f / 256.0f);
}

extern "C" void kernel_launch(void* const* d_in, const int* in_sizes, int n_in,
                              void* d_out, int out_size, void* d_ws, size_t ws_size,
                              hipStream_t stream) {
    const float* logits = (const float*)d_in[0];  // [4,1,32,128,128] fp32
    const float* pts    = (const float*)d_in[1];  // [4,64,3] fp32
    float* part = (float*)d_ws;                   // 512*64 floats = 128 KB
    float* out  = (float*)d_out;                  // scalar fp32

    k_fused<<<dim3(512), dim3(256), 0, stream>>>(logits, pts, part);
    k_finish<<<dim3(1), dim3(256), 0, stream>>>(part, out);
}

// Round 5
// 74.929 us; speedup vs baseline: 1.1667x; 1.1391x over previous
//
#include <hip/hip_runtime.h>
#include <math.h>

// Problem constants (fixed by reference)
constexpr int N_ = 4, P_ = 64, Z_ = 32, Y_ = 128, X_ = 128;
constexpr float EPSF = 1e-8f;
constexpr float INV2S2 = 0.125f;   // 1/(2*sigma^2), sigma = 2

// ---------------------------------------------------------------------------
// Fused kernel: separable Gaussian factors computed in-register/LDS,
// per-voxel denom + m accumulation, per-block partial written to a PRIVATE
// workspace slot (full overwrite -> no pre-zero needed despite 0xAA poison,
// no atomics).
//
// Grid: 512 blocks = (n, z, y-half, x-half); 256 threads = 4 waves.
// Each wave owns one y-row per pass (16 passes), each thread one x-column.
// kzy[row][p] in LDS (16/thread exps), kxr[p] in VGPRs (64/thread exps).
// Product of 2 exps == reference single exp to ~ulp wherever K exceeds the
// 1e-8 denominator floor. kkx[p]=kzy*kxr computed once/pass; denom = 4-way
// partial sum; macc += kkx*w reuses it. One fp32 divide per voxel.
//
// Epilogue: butterfly ARRAY-HALVING reduction (6 stages, 63 shuffles/thread
// instead of 64p x 6 = 384) — the DS pipe is per-CU and shared by 8 waves,
// so the old scheme cost ~18K DS cycles/CU (~7.7 us); this cuts it ~6x.
// After the stages lane l holds the wave total for p == l.
// ---------------------------------------------------------------------------
__global__ __launch_bounds__(256, 2) void k_fused(const float* __restrict__ logits,
                                                  const float* __restrict__ pts,
                                                  float* __restrict__ part) {
    const int b = blockIdx.x;          // 512 blocks: [n:2][z:5][yh:1][xh:1]
    const int n  = b >> 7;
    const int z  = (b >> 2) & 31;
    const int y0 = ((b >> 1) & 1) * 64;
    const int x0 = (b & 1) * 64;

    const int tid = threadIdx.x;
    const int lane = tid & 63;
    const int wid = tid >> 6;

    __shared__ float ptsn[192];        // pts[n] = [64][3]
    __shared__ float kzy[64 * 64];     // [row][p], 16 KB
    __shared__ float wsum[4][64];

    if (tid < 192) ptsn[tid] = pts[n * 192 + tid];
    __syncthreads();

    // kzy tile: 4096 exps / 256 threads = 16 per thread.
    for (int i = tid; i < 64 * 64; i += 256) {
        int row = i >> 6, p = i & 63;  // ptsn stride-3 reads: 2-way alias = free
        float dz = (float)z - ptsn[p * 3 + 0];
        float dy = (float)(y0 + row) - ptsn[p * 3 + 1];
        kzy[i] = __expf(-(dz * dz + dy * dy) * INV2S2);
    }

    const int x = x0 + lane;
    float kxr[64], macc[64];
    #pragma unroll
    for (int p = 0; p < 64; ++p) {
        float dx = (float)x - ptsn[p * 3 + 2];
        kxr[p] = __expf(-dx * dx * INV2S2);
        macc[p] = 0.0f;
    }
    __syncthreads();

    const float* lbase = logits + (size_t)((n * Z_ + z) * Y_ + y0) * X_ + x;

    float lg = lbase[wid * X_];        // prefetch pass-0 logit
    #pragma unroll 1
    for (int pass = 0; pass < 16; ++pass) {
        const int row = pass * 4 + wid;           // wave-uniform row
        float lg_next = 0.0f;
        if (pass < 15) lg_next = lbase[(row + 4) * X_];   // prefetch next pass

        const float4* kr = (const float4*)(&kzy[row * 64]);
        float kkx[64];
        float d0 = 0.f, d1 = 0.f, d2 = 0.f, d3 = 0.f;
        #pragma unroll
        for (int q = 0; q < 16; ++q) {
            const float4 k4 = kr[q];              // broadcast b128 read
            kkx[4*q+0] = k4.x * kxr[4*q+0]; d0 += kkx[4*q+0];
            kkx[4*q+1] = k4.y * kxr[4*q+1]; d1 += kkx[4*q+1];
            kkx[4*q+2] = k4.z * kxr[4*q+2]; d2 += kkx[4*q+2];
            kkx[4*q+3] = k4.w * kxr[4*q+3]; d3 += kkx[4*q+3];
        }
        const float denom = (d0 + d1) + (d2 + d3);
        // w = sigmoid(lg) / max(denom, EPS): one fp32 divide
        const float w = 1.0f / ((1.0f + __expf(-lg)) * fmaxf(denom, EPSF));

        #pragma unroll
        for (int p = 0; p < 64; ++p) macc[p] = fmaf(kkx[p], w, macc[p]);
        lg = lg_next;
    }

    // Butterfly array-halving reduction: stage D exchanges D values with the
    // lane D apart; the (lane & D) half keeps p-range [D,2D). All indices are
    // compile-time after unroll (no dynamic VGPR indexing -> no scratch).
    float* v = macc;
#define RED_STAGE(D)                                              \
    {                                                             \
        const bool hi = (lane & (D)) != 0;                        \
        _Pragma("unroll")                                         \
        for (int i = 0; i < (D); ++i) {                           \
            float mine = hi ? v[i + (D)] : v[i];                  \
            float send = hi ? v[i] : v[i + (D)];                  \
            float got = __shfl_xor(send, (D), 64);                \
            v[i] = mine + got;                                    \
        }                                                         \
    }
    RED_STAGE(32) RED_STAGE(16) RED_STAGE(8)
    RED_STAGE(4)  RED_STAGE(2)  RED_STAGE(1)
#undef RED_STAGE
    // v[0] = wave total for p == lane.
    wsum[wid][lane] = v[0];
    __syncthreads();
    if (tid < 64) {
        float s = (wsum[0][tid] + wsum[1][tid]) + (wsum[2][tid] + wsum[3][tid]);
        part[b * 64 + tid] = s;        // private slot: plain store, no atomic
    }
}

// ---------------------------------------------------------------------------
// Finish kernel: m[n][p] = sum of that n's 128 block-partials, then
// loss = mean_{n,p} -log(max(m, EPS)). 1 block x 1024 threads: each (n,p)
// pair gets 4 threads summing 32 partials each (cuts the serial L2-latency
// chain 4x vs 128 loads/thread), combined in LDS.
// ---------------------------------------------------------------------------
__global__ __launch_bounds__(1024) void k_finish(const float* __restrict__ part,
                                                 float* __restrict__ out) {
    const int t = threadIdx.x;
    const int pair = t & 255;          // (n,p): n = pair>>6, p = pair&63
    const int quarter = t >> 8;        // which 32-block slice
    const int n = pair >> 6, p = pair & 63;

    const float* base = part + (size_t)(n * 128 + quarter * 32) * 64 + p;
    float s0 = 0.f, s1 = 0.f, s2 = 0.f, s3 = 0.f;
    #pragma unroll 2
    for (int j = 0; j < 32; j += 4) {  // independent accumulators
        s0 += base[(j + 0) * 64];
        s1 += base[(j + 1) * 64];
        s2 += base[(j + 2) * 64];
        s3 += base[(j + 3) * 64];
    }
    __shared__ float red[4][256];
    red[quarter][pair] = (s0 + s1) + (s2 + s3);
    __syncthreads();

    if (t < 256) {
        const float m = (red[0][t] + red[1][t]) + (red[2][t] + red[3][t]);
        float l = -logf(fmaxf(m, EPSF));
        #pragma unroll
        for (int off = 32; off > 0; off >>= 1) l += __shfl_xor(l, off, 64);
        __shared__ float red2[4];
        if ((t & 63) == 0) red2[t >> 6] = l;
        __syncthreads();
        if (t == 0) out[0] = (red2[0] + red2[1] + red2[2] + red2[3]) * (1.0f / 256.0f);
    }
}

extern "C" void kernel_launch(void* const* d_in, const int* in_sizes, int n_in,
                              void* d_out, int out_size, void* d_ws, size_t ws_size,
                              hipStream_t stream) {
    const float* logits = (const float*)d_in[0];  // [4,1,32,128,128] fp32
    const float* pts    = (const float*)d_in[1];  // [4,64,3] fp32
    float* part = (float*)d_ws;                   // 512*64 floats = 128 KB
    float* out  = (float*)d_out;                  // scalar fp32

    k_fused<<<dim3(512), dim3(256), 0, stream>>>(logits, pts, part);
    k_finish<<<dim3(1), dim3(1024), 0, stream>>>(part, out);
}